// Round 8
// baseline (163.312 us; speedup 1.0000x reference)
//
#include <hip/hip_runtime.h>
#include <math.h>

#define B_ 64
#define IC 2048
#define OC 32
#define OD 16
#define ID 8

#define GLOAD_LDS16(gp, lp)                                                       \
  __builtin_amdgcn_global_load_lds((const __attribute__((address_space(1))) void*)(gp), \
                                   (__attribute__((address_space(3))) void*)(lp), \
                                   16, 0, 0)

__device__ __forceinline__ float dot8(const float4 w0, const float4 w1,
                                      const float4 xa, const float4 xb) {
  return w0.x*xa.x + w0.y*xa.y + w0.z*xa.z + w0.w*xa.w
       + w1.x*xb.x + w1.y*xb.y + w1.z*xb.z + w1.w*xb.w;
}

// ---------------------------------------------------------------------------
// Fused routing pass (b_k = u.(v1+...+vk) algebra; unnormalized p=exp(u.vs),
// Z applied in reduceSquash).
//
// R8 geometry: grid = 4(bh) x NCH (XCD-remapped), block = 512 threads
// (8 waves). wv=t>>6: og=wv>>2 selects o-half, bset=wv&3 selects 4 b's.
// Lane: op=lane>>2 -> o = og*16+op; dq=lane&3 -> d in [dq*4,dq*4+4).
// Thread tile: 1 o x 4 d x 4 b = 128 FMA per i against only 8 W ds_read_b128
// + 8 x broadcast ds_reads (same-addr, conflict-free, in-order lgkmcnt —
// R7's scalar x loads forced lgkmcnt(0) drains of ~300cy SMEM latency each
// iteration; everything now stays on the fine-grained ds path).
//
// W[i] (16KB) double-buffered via global_load_lds (2 insts/thread), source
// XOR-swizzled (involution p -> (p&~7)|((p&7)^((p>>3)&7))) so the
// per-thread read of 8 contiguous f4 is bank-conflict-free.
// x window (16b x 8i, 4KB) staged once per 8-i subwindow.
// ---------------------------------------------------------------------------
template<bool WEIGHTED, int NCH>
__global__ __launch_bounds__(512) void fusedK(
    const float* __restrict__ x, const float* __restrict__ W,
    const float* __restrict__ vs, float* __restrict__ part,
    float* __restrict__ zpart)
{
  constexpr int CI  = IC / NCH;
  constexpr int NSW = CI / 8;
  const int t    = threadIdx.x;
  const int xcd  = blockIdx.x & 7;
  const int q    = blockIdx.x >> 3;
  const int ch   = (q >> 2) * 8 + xcd;
  const int bh   = q & 3;
  const int lane = t & 63;
  const int wv   = t >> 6;
  const int og   = wv >> 2;
  const int bset = wv & 3;
  const int op   = lane >> 2;
  const int dq   = lane & 3;
  const int o    = og * 16 + op;
  const int rot  = lane & 7;
  const int i0   = ch * CI;
  const int jb   = o * 32 + dq * 8;      // thread's W f4 base
  const int bl0  = bset * 4;             // block-local first b
  const int b0   = bh * 16 + bl0;        // global first b

  __shared__ float Wbuf[2][4096];        // 2 x 16 KB
  __shared__ float xall[1024];           // 16 b x 8 i x 8 m = 4 KB

  const float4* Wg = (const float4*)W;
  const float4* xg = (const float4*)x;

  float4 acc[4];
  float  zacc[4];
  float4 vreg[4];
#pragma unroll
  for (int k = 0; k < 4; ++k) { acc[k] = make_float4(0,0,0,0); zacc[k] = 0.f; }

  if constexpr (WEIGHTED) {
#pragma unroll
    for (int bb = 0; bb < 4; ++bb)
      vreg[bb] = *(const float4*)(vs + ((size_t)(b0 + bb) * 32 + o) * 16 + dq * 4);
  }

  auto stageW = [&](int i, int nb) {
    const float4* Wi = Wg + (size_t)i * 1024;
#pragma unroll
    for (int k = 0; k < 2; ++k) {
      const int p   = wv * 128 + k * 64 + lane;
      const int src = (p & ~7) | ((p & 7) ^ ((p >> 3) & 7));
      GLOAD_LDS16(Wi + src, &Wbuf[nb][(wv * 128 + k * 64) * 4]);
    }
  };

  auto stageX = [&](int sw) {
    // xall f4 idx t (t<256): b=t>>4, r=t&15 -> i=r>>1, half=r&1; linear dest
    if (t < 256) {
      const int b  = t >> 4, r = t & 15;
      const int ia = i0 + sw * 8 + (r >> 1);
      GLOAD_LDS16(xg + ((size_t)(bh * 16 + b) * IC + ia) * 2 + (r & 1),
                  &xall[(wv * 64) * 4]);
    }
  };

  stageX(0);
  stageW(i0, 0);
  int cur = 0;

#pragma unroll 1
  for (int sw = 0; sw < NSW; ++sw) {
#pragma unroll 1
    for (int j = 0; j < 8; ++j) {
      const int ii = sw * 8 + j;

      __syncthreads();                          // drains stage issued last iter
      if (ii + 1 < CI) stageW(i0 + ii + 1, cur ^ 1);

      const float* Wb = &Wbuf[cur][0];
      float4 wr[8];
#pragma unroll
      for (int r = 0; r < 8; ++r)
        wr[r] = *(const float4*)&Wb[(jb + (r ^ rot)) * 4];

#pragma unroll
      for (int bb = 0; bb < 4; ++bb) {
        const int bl = bl0 + bb;
        const float4 xa = *(const float4*)&xall[bl * 64 + j * 8];      // broadcast
        const float4 xc = *(const float4*)&xall[bl * 64 + j * 8 + 4];  // broadcast
        float4 u;
        u.x = dot8(wr[0], wr[1], xa, xc);
        u.y = dot8(wr[2], wr[3], xa, xc);
        u.z = dot8(wr[4], wr[5], xa, xc);
        u.w = dot8(wr[6], wr[7], xa, xc);
        if constexpr (!WEIGHTED) {
          acc[bb].x += u.x; acc[bb].y += u.y; acc[bb].z += u.z; acc[bb].w += u.w;
        } else {
          const float4 vv = vreg[bb];
          float pd = u.x * vv.x + u.y * vv.y + u.z * vv.z + u.w * vv.w;
          pd += __shfl_xor(pd, 1);              // reduce over dq (lane bits 0-1)
          pd += __shfl_xor(pd, 2);
          const float p = __expf(pd);           // unnormalized c
          acc[bb].x = fmaf(p, u.x, acc[bb].x);
          acc[bb].y = fmaf(p, u.y, acc[bb].y);
          acc[bb].z = fmaf(p, u.z, acc[bb].z);
          acc[bb].w = fmaf(p, u.w, acc[bb].w);
          zacc[bb] += p;
        }
      }
      cur ^= 1;
    }
    if (sw + 1 < NSW) {
      __syncthreads();              // all waves done reading xall window
      stageX(sw + 1);               // drained by next top-of-iteration barrier
    }
  }

  // epilogue: part[ch][b][o][d] f4-coalesced; zpart[ch][b*32+o] (dq==0)
  float4* part4 = (float4*)part;
#pragma unroll
  for (int bb = 0; bb < 4; ++bb) {
    const int b = b0 + bb;
    part4[((size_t)ch * 64 + b) * 128 + o * 4 + dq] = acc[bb];
    if constexpr (WEIGHTED) {
      if (dq == 0) zpart[(size_t)ch * 2048 + b * 32 + o] = zacc[bb];
    }
  }
}

// ---------------------------------------------------------------------------
// Reduce s partials over chunks, normalize, squash.
// PASS 0: s*=1/2048, vs[g]  = v ; PASS 1: s*=rz, vs[g] += v ;
// PASS 2: s*=rz, out[g] = v.   grid 128 x 256; g = b*512 + o*16 + d.
// ---------------------------------------------------------------------------
template<int PASS, int NCH>
__global__ __launch_bounds__(256) void reduceSquash(
    const float* __restrict__ part, const float* __restrict__ rz,
    float* __restrict__ vsio, float* __restrict__ out)
{
  const int g = blockIdx.x * 256 + threadIdx.x;
  float s = 0.f;
#pragma unroll 8
  for (int ch = 0; ch < NCH; ++ch) s += part[(size_t)ch * 32768 + g];
  if constexpr (PASS == 0) s *= (1.f / 2048.f);
  else                     s *= rz[g >> 4];

  float sq = s * s;
#pragma unroll
  for (int k = 1; k < 16; k <<= 1) sq += __shfl_xor(sq, k);   // sum over d
  const float f = (sq / (1.f + sq)) * rsqrtf(sq + 1e-9f);
  const float v = s * f;

  if constexpr (PASS == 0)      vsio[g] = v;
  else if constexpr (PASS == 1) vsio[g] += v;
  else                          out[g] = v;
}

// ---------------------------------------------------------------------------
// Z reduction: rz[b*32+o] = 1 / sum_ch zpart. grid 8 x 256.
// ---------------------------------------------------------------------------
template<int NCH>
__global__ __launch_bounds__(256) void zredK(
    const float* __restrict__ zpart, float* __restrict__ rz)
{
  const int j = blockIdx.x * 256 + threadIdx.x;
  float zs = 0.f;
#pragma unroll 8
  for (int ch = 0; ch < NCH; ++ch) zs += zpart[(size_t)ch * 2048 + j];
  rz[j] = 1.f / zs;
}

// ---------------------------------------------------------------------------
extern "C" void kernel_launch(void* const* d_in, const int* in_sizes, int n_in,
                              void* d_out, int out_size, void* d_ws, size_t ws_size,
                              hipStream_t stream) {
  (void)in_sizes; (void)n_in; (void)out_size;
  const float* x = (const float*)d_in[0];
  const float* W = (const float*)d_in[1];
  float* out = (float*)d_out;
  float* ws  = (float*)d_ws;

  auto run = [&](auto tag) {
    constexpr int NCH = decltype(tag)::value;
    float* part  = ws;                                 // [NCH][64][32][16]
    float* zpart = part + (size_t)NCH * 32768;         // [NCH][2048]
    float* rz    = zpart + (size_t)NCH * 2048;         // [2048]
    float* vsb   = rz + 2048;                          // vs running sum [32768]

    const dim3 gF(4 * NCH), bF(512), b256(256), gR(128);
    // pass 1: uniform c -> v1 (vs = v1)
    fusedK<false, NCH><<<gF, bF, 0, stream>>>(x, W, nullptr, part, nullptr);
    reduceSquash<0, NCH><<<gR, b256, 0, stream>>>(part, nullptr, vsb, nullptr);
    // pass 2: p = exp(u.v1) -> v2; vs = v1+v2
    fusedK<true, NCH><<<gF, bF, 0, stream>>>(x, W, vsb, part, zpart);
    zredK<NCH><<<dim3(8), b256, 0, stream>>>(zpart, rz);
    reduceSquash<1, NCH><<<gR, b256, 0, stream>>>(part, rz, vsb, nullptr);
    // pass 3: p = exp(u.(v1+v2)) -> v3 = output
    fusedK<true, NCH><<<gF, bF, 0, stream>>>(x, W, vsb, part, zpart);
    zredK<NCH><<<dim3(8), b256, 0, stream>>>(zpart, rz);
    reduceSquash<2, NCH><<<gR, b256, 0, stream>>>(part, rz, nullptr, out);
  };

  const size_t need256 =
      ((size_t)256 * 32768 + 256ul * 2048 + 2048 + 32768) * 4;
  if (ws_size >= need256) run(std::integral_constant<int, 256>{});
  else                    run(std::integral_constant<int, 64>{});
}